// Round 14
// baseline (209.343 us; speedup 1.0000x reference)
//
#include <hip/hip_runtime.h>
#include <hip/hip_bf16.h>

// 2-layer LSTM (H=32, T=512, I=1) + FC(1) + ReLU, fused, ZERO-SELECT
// 16-wave unit-split, 16 batches/block, ONE cell per lane. Block = 1024
// threads = 16 waves: w0-7 = layer-0 unit-groups (4 units each: 4V..4V+3),
// w8-15 = layer-1 unit-groups (one step behind). Weight rows permuted so
// tile row rho = gate(rho&3) of unit 4V+(rho>>2): lane m's 4 D-regs =
// (i,f,g,o) of unit 4V+m -> no gate select. col = batch (16 distinct).
// 256 blocks x 16 waves = 4096 waves = 4/SIMD (vs R13's 2/SIMD): double
// the independent recurrence chains per SIMD at identical chip-wide issue.
// h exchanged as packed bf16 pairs via LDS (stride-20 rows, <=2-way);
// double-buffered by parity, one __syncthreads per step. Bias in MFMA
// C-in; merged-rcp CELL (7 trans); pre-zeroed LDS.

typedef __attribute__((ext_vector_type(8))) short bf16x8;
typedef __attribute__((ext_vector_type(4))) float f32x4;
typedef __attribute__((ext_vector_type(4))) int   i32x4;

#define HID 32
#define SEQ 512
#define L2E 1.4426950408889634f
#define LSTR 20   // LDS h-row stride in dwords (16 used + 4 pad, 16B-aligned)

static __device__ __forceinline__ float fexp2(float x){ return __builtin_amdgcn_exp2f(x); }
static __device__ __forceinline__ float frcp (float x){ return __builtin_amdgcn_rcpf(x); }
static __device__ __forceinline__ short f2bf(float f){
  unsigned u = __builtin_bit_cast(unsigned, f);
  u = (u + 0x7fffu + ((u >> 16) & 1u)) >> 16;
  return (short)u;
}

// fused LSTM cell, merged-rcp form. Gates pre-scaled (i,f,o by -log2e;
// g by +2log2e):  I=e^-i, F=e^-f, O=e^-o, G=e^{2g}.
#define CELL(gi, gf, gg, go, cvr, hout) do {                         \
  const float I_ = fexp2(gi), G_ = fexp2(gg);                        \
  const float F_ = fexp2(gf), O_ = fexp2(go);                        \
  const float a_ = 1.f + I_, b_ = 1.f + G_, c_ = 1.f + F_;           \
  const float P1_ = a_ * b_;                                         \
  const float R_  = frcp(c_ * P1_);                                  \
  const float fv_ = P1_ * R_;                                        \
  const float ig_ = (G_ - 1.f) * (c_ * R_);                          \
  (cvr) = fmaf(fv_, (cvr), ig_);                                     \
  const float C2_ = fexp2((cvr) * (2.f * L2E));                      \
  (hout) = (C2_ - 1.f) * frcp((1.f + O_) * (1.f + C2_));             \
} while (0)

// pack own h with partner lane (l^16 = m^1, same col) -> bf16 pair dword
#define HPACK(hv, pk) do {                                                    \
  const int pa_ = __builtin_amdgcn_ds_swizzle(__builtin_bit_cast(int, (hv)), 0x401F); \
  asm("v_cvt_pk_bf16_f32 %0, %1, %2" : "=v"(pk)                               \
      : "v"(hv), "v"(__builtin_bit_cast(float, pa_)));                        \
} while (0)

__global__ __launch_bounds__(1024, 4) void lstm2_zs16_kernel(
    const float* __restrict__ x,
    const float* __restrict__ Wih0, const float* __restrict__ Whh0,
    const float* __restrict__ bih0, const float* __restrict__ bhh0,
    const float* __restrict__ Wih1, const float* __restrict__ Whh1,
    const float* __restrict__ bih1, const float* __restrict__ bhh1,
    const float* __restrict__ Wfc, const float* __restrict__ bfc,
    float* __restrict__ out)
{
  const int tid = threadIdx.x;
  const int w   = tid >> 6;          // 0-7: L0 groups; 8-15: L1 groups
  const int l   = tid & 63;
  const int m   = l >> 4;            // k-group; owns unit 4V+m
  const int col = l & 15;            // batch slot (16 batches/block)
  const int V   = w & 7;             // unit group: units 4V..4V+3
  const bool isL1 = (w >= 8);
  const int unit = 4 * V + m;        // owned cell unit within layer

  __shared__ int   bufH0[2][16 * LSTR];   // [parity][batch*LSTR + unitpair]
  __shared__ int   bufH1[2][16 * LSTR];
  __shared__ float bufFC[8][16];

  // zero-init exchange buffers (kills all t=0 special cases)
  if (tid < 2 * 16 * LSTR) {
    ((int*)bufH0)[tid] = 0;
    ((int*)bufH1)[tid] = 0;
  }
  __syncthreads();

  // ---- weights: tile row rho = gate(rho&3) of unit 4V+(rho>>2).
  //      Lane supplies A row = col. Pre-scaled: i,f,o -> -log2e; g -> +2log2e.
  const float* Wrec = isL1 ? Whh1 : Whh0;
  const float* Bi   = isL1 ? bih1 : bih0;
  const float* Bh   = isL1 ? bhh1 : bhh0;
  const int   gcol  = col & 3;             // gate type this lane's A-row feeds
  const float scA   = (gcol == 2) ? (2.0f * L2E) : (-L2E);
  const int   ga    = gcol * 32 + 4 * V + (col >> 2);  // gate row in W
  bf16x8 wfR, wfI;
  f32x4  cb;
  float  w0x[4];
  #pragma unroll
  for (int j = 0; j < 8; ++j) {
    wfR[j] = f2bf(scA * Wrec[ga * HID + (8 * m + j)]);
    wfI[j] = isL1 ? f2bf(scA * Wih1[ga * HID + (8 * m + j)]) : (short)0;
  }
  #pragma unroll
  for (int rr = 0; rr < 4; ++rr) {
    const float sc = (rr == 2) ? (2.0f * L2E) : (-L2E);
    cb[rr]  = sc * (Bi[rr * 32 + unit] + Bh[rr * 32 + unit]);
    w0x[rr] = isL1 ? 0.f : sc * Wih0[rr * 32 + unit];
  }
  const float wfc = isL1 ? Wfc[unit] : 0.f;

  float cv = 0.f, hn = 0.f;
  const float* xb = x + (size_t)(blockIdx.x * 16 + col) * SEQ;
  const int  rd = col * LSTR + 4 * m;                 // b128 read: units 8m..8m+7
  const int  wb = col * LSTR + 2 * V + (m >> 1);      // write: pair dword
  const bool wr = ((m & 1) == 0);                     // even-m lanes write

  for (int k = 0; k < SEQ / 4; ++k) {
    float4 xv = {0.f, 0.f, 0.f, 0.f};
    if (!isL1) xv = *reinterpret_cast<const float4*>(xb + k * 4);
    #pragma unroll
    for (int uu = 0; uu < 4; ++uu) {
      const int par = uu & 1;
      if (!isL1) {
        // ---- L0: h0(i) from h0(i-1) at parity (i+1)&1 ----
        const i32x4 hv = *(const i32x4*)&bufH0[par ^ 1][rd];
        const bf16x8 hf = __builtin_bit_cast(bf16x8, hv);
        const f32x4 A = __builtin_amdgcn_mfma_f32_16x16x32_bf16(wfR, hf, cb, 0, 0, 0);
        const float xt = (uu == 0) ? xv.x : (uu == 1) ? xv.y : (uu == 2) ? xv.z : xv.w;
        // regs ARE (i,f,g,o) of the owned unit -- zero select
        CELL(fmaf(w0x[0], xt, A[0]), fmaf(w0x[1], xt, A[1]),
             fmaf(w0x[2], xt, A[2]), fmaf(w0x[3], xt, A[3]), cv, hn);
        int pk;
        HPACK(hn, pk);
        if (wr) bufH0[par][wb] = pk;
      } else if (uu > 0 || k > 0) {
        // ---- L1: h1(i-1); reads h0(i-1) par^1, h1(i-2) par ----
        const i32x4 h0v = *(const i32x4*)&bufH0[par ^ 1][rd];
        const i32x4 h1v = *(const i32x4*)&bufH1[par][rd];
        const bf16x8 h0f = __builtin_bit_cast(bf16x8, h0v);
        const bf16x8 h1f = __builtin_bit_cast(bf16x8, h1v);
        __builtin_amdgcn_s_setprio(1);
        f32x4 A = __builtin_amdgcn_mfma_f32_16x16x32_bf16(wfI, h0f, cb, 0, 0, 0);
        A = __builtin_amdgcn_mfma_f32_16x16x32_bf16(wfR, h1f, A, 0, 0, 0);
        __builtin_amdgcn_s_setprio(0);
        CELL(A[0], A[1], A[2], A[3], cv, hn);
        int pk;
        HPACK(hn, pk);
        if (wr) bufH1[par ^ 1][wb] = pk;   // h1(i-1) -> parity (i-1)&1
      }
      __syncthreads();
    }
  }

  // ---- epilogue: i = 512 for L1 -> h1(511); then FC + ReLU ----
  if (isL1) {
    const i32x4 h0v = *(const i32x4*)&bufH0[1][rd];   // h0(511), parity 1
    const i32x4 h1v = *(const i32x4*)&bufH1[0][rd];   // h1(510), parity 0
    const bf16x8 h0f = __builtin_bit_cast(bf16x8, h0v);
    const bf16x8 h1f = __builtin_bit_cast(bf16x8, h1v);
    f32x4 A = __builtin_amdgcn_mfma_f32_16x16x32_bf16(wfI, h0f, cb, 0, 0, 0);
    A = __builtin_amdgcn_mfma_f32_16x16x32_bf16(wfR, h1f, A, 0, 0, 0);
    CELL(A[0], A[1], A[2], A[3], cv, hn);
    float part = hn * wfc;
    part += __shfl_xor(part, 16);   // sum over m (4 owned units)
    part += __shfl_xor(part, 32);
    if (l < 16) bufFC[V][l] = part;  // l<16 -> m==0, col=l
  }
  __syncthreads();
  if (w == 8 && l < 16) {
    float o = bfc[0];
    #pragma unroll
    for (int v = 0; v < 8; ++v) o += bufFC[v][l];
    out[blockIdx.x * 16 + l] = o > 0.f ? o : 0.f;
  }
}

extern "C" void kernel_launch(void* const* d_in, const int* in_sizes, int n_in,
                              void* d_out, int out_size, void* d_ws, size_t ws_size,
                              hipStream_t stream) {
  const float* x    = (const float*)d_in[0];
  const float* Wih0 = (const float*)d_in[1];
  const float* Whh0 = (const float*)d_in[2];
  const float* bih0 = (const float*)d_in[3];
  const float* bhh0 = (const float*)d_in[4];
  const float* Wih1 = (const float*)d_in[5];
  const float* Whh1 = (const float*)d_in[6];
  const float* bih1 = (const float*)d_in[7];
  const float* bhh1 = (const float*)d_in[8];
  const float* Wfc  = (const float*)d_in[9];
  const float* bfc  = (const float*)d_in[10];

  const int B = 4096;
  const int grid = B / 16;   // 256 blocks x 16 waves = 4096 waves -> 4/SIMD
  lstm2_zs16_kernel<<<grid, 1024, 0, stream>>>(
      x, Wih0, Whh0, bih0, bhh0, Wih1, Whh1, bih1, bhh1, Wfc, bfc,
      (float*)d_out);
}

// Round 15
// 177.427 us; speedup vs baseline: 1.1799x; 1.1799x over previous
//
#include <hip/hip_runtime.h>
#include <hip/hip_bf16.h>

// 2-layer LSTM (H=32, T=512, I=1) + FC(1) + ReLU, fused, ZERO-SELECT
// 8-wave unit-split, 16 batches/block (R13 champion shape) with the
// per-step critical path cut down:
//  * adjacent-unit tiles: tile t row rho = gate(rho&3) of unit
//    8V+2*(rho>>2)+t -> lane m owns units 8V+2m (t=0) and 8V+2m+1 (t=1),
//    an ADJACENT pair: h-publish = 1 cvt_pk + 1 ds_write_b32 by all lanes
//    (deletes the ds_swizzle round-trip from the recurrence path).
//  * L1 lags 2 steps: at iter i it computes h1(i-2) using h0(i-2) that was
//    PREFETCHED into registers during iter i-1 (4-parity h0 buffer) -- the
//    h0 read latency is off the path; only the h1 self-recurrence read
//    remains. h1 reads issue before the h0 prefetch so the compiler waits
//    lgkmcnt(1) and keeps the prefetch in flight across the compute.
// Zero gate select; bias in MFMA C-in; merged-rcp CELL (7 trans);
// double-buffered by parity, one __syncthreads per step; pre-zeroed LDS.
// 256 blocks x 8 waves = 2048 waves = 2/SIMD.

typedef __attribute__((ext_vector_type(8))) short bf16x8;
typedef __attribute__((ext_vector_type(4))) float f32x4;
typedef __attribute__((ext_vector_type(4))) int   i32x4;

#define HID 32
#define SEQ 512
#define L2E 1.4426950408889634f
#define LSTR 20   // LDS h-row stride in dwords (16 used + 4 pad, 16B-aligned)

static __device__ __forceinline__ float fexp2(float x){ return __builtin_amdgcn_exp2f(x); }
static __device__ __forceinline__ float frcp (float x){ return __builtin_amdgcn_rcpf(x); }
static __device__ __forceinline__ short f2bf(float f){
  unsigned u = __builtin_bit_cast(unsigned, f);
  u = (u + 0x7fffu + ((u >> 16) & 1u)) >> 16;
  return (short)u;
}

// fused LSTM cell, merged-rcp form. Gates pre-scaled (i,f,o by -log2e;
// g by +2log2e):  I=e^-i, F=e^-f, O=e^-o, G=e^{2g}.
#define CELL(gi, gf, gg, go, cvr, hout) do {                         \
  const float I_ = fexp2(gi), G_ = fexp2(gg);                        \
  const float F_ = fexp2(gf), O_ = fexp2(go);                        \
  const float a_ = 1.f + I_, b_ = 1.f + G_, c_ = 1.f + F_;           \
  const float P1_ = a_ * b_;                                         \
  const float R_  = frcp(c_ * P1_);                                  \
  const float fv_ = P1_ * R_;                                        \
  const float ig_ = (G_ - 1.f) * (c_ * R_);                          \
  (cvr) = fmaf(fv_, (cvr), ig_);                                     \
  const float C2_ = fexp2((cvr) * (2.f * L2E));                      \
  (hout) = (C2_ - 1.f) * frcp((1.f + O_) * (1.f + C2_));             \
} while (0)

__global__ __launch_bounds__(512, 2) void lstm2_zs2_kernel(
    const float* __restrict__ x,
    const float* __restrict__ Wih0, const float* __restrict__ Whh0,
    const float* __restrict__ bih0, const float* __restrict__ bhh0,
    const float* __restrict__ Wih1, const float* __restrict__ Whh1,
    const float* __restrict__ bih1, const float* __restrict__ bhh1,
    const float* __restrict__ Wfc, const float* __restrict__ bfc,
    float* __restrict__ out)
{
  const int tid = threadIdx.x;
  const int w   = tid >> 6;          // 0-3: L0 groups; 4-7: L1 groups
  const int l   = tid & 63;
  const int m   = l >> 4;            // k-group; owns units 8V+2m, 8V+2m+1
  const int col = l & 15;            // batch slot (16 batches/block)
  const int V   = w & 3;             // unit group: units 8V..8V+7
  const bool isL1 = (w >= 4);

  __shared__ int   bufH0[4][16 * LSTR];   // 4 parities (lag-2 prefetch)
  __shared__ int   bufH1[2][16 * LSTR];
  __shared__ float bufFC[4][16];

  // zero-init exchange buffers (kills all t=0 special cases)
  for (int i = tid; i < 6 * 16 * LSTR; i += 512)
    ((int*)bufH0)[i] = 0;   // bufH0[4] and bufH1[2] are contiguous? no --
  // (separate arrays: zero them individually)
  for (int i = tid; i < 4 * 16 * LSTR; i += 512) ((int*)bufH0)[i] = 0;
  for (int i = tid; i < 2 * 16 * LSTR; i += 512) ((int*)bufH1)[i] = 0;
  __syncthreads();

  // ---- weights: tile t row rho = gate(rho&3) of unit 8V+2*(rho>>2)+t.
  //      Lane supplies A row = col. Pre-scaled: i,f,o -> -log2e; g -> +2log2e.
  const float* Wrec = isL1 ? Whh1 : Whh0;
  const float* Bi   = isL1 ? bih1 : bih0;
  const float* Bh   = isL1 ? bhh1 : bhh0;
  const int   gcol  = col & 3;             // gate type this lane's A-row feeds
  const float scA   = (gcol == 2) ? (2.0f * L2E) : (-L2E);
  bf16x8 wfR[2], wfI[2];
  f32x4  cb[2];
  float  w0x[2][4];
  #pragma unroll
  for (int t = 0; t < 2; ++t) {
    const int ga = gcol * 32 + 8 * V + 2 * (col >> 2) + t;  // A-row unit's gate row
    #pragma unroll
    for (int j = 0; j < 8; ++j) {
      wfR[t][j] = f2bf(scA * Wrec[ga * HID + (8 * m + j)]);
      wfI[t][j] = isL1 ? f2bf(scA * Wih1[ga * HID + (8 * m + j)]) : (short)0;
    }
    const int uc = 8 * V + 2 * m + t;            // owned cell unit (tile t)
    #pragma unroll
    for (int rr = 0; rr < 4; ++rr) {
      const float sc = (rr == 2) ? (2.0f * L2E) : (-L2E);
      cb[t][rr]  = sc * (Bi[rr * 32 + uc] + Bh[rr * 32 + uc]);
      w0x[t][rr] = isL1 ? 0.f : sc * Wih0[rr * 32 + uc];
    }
  }
  const float wfcA = isL1 ? Wfc[8 * V + 2 * m]     : 0.f;
  const float wfcB = isL1 ? Wfc[8 * V + 2 * m + 1] : 0.f;

  float cvA = 0.f, cvB = 0.f, hA = 0.f, hB = 0.f;
  i32x4 h0pre = {0, 0, 0, 0};        // L1: h0(i-2) register prefetch
  const float* xb = x + (size_t)(blockIdx.x * 16 + col) * SEQ;
  const int  rd = col * LSTR + 4 * m;            // b128 read: units 8m..8m+7
  const int  wb = col * LSTR + 4 * V + m;        // b32 write: own unit pair

  for (int k = 0; k < SEQ / 4; ++k) {
    float4 xv = {0.f, 0.f, 0.f, 0.f};
    if (!isL1) xv = *reinterpret_cast<const float4*>(xb + k * 4);
    #pragma unroll
    for (int uu = 0; uu < 4; ++uu) {
      if (!isL1) {
        // ---- L0: h0(i) from h0(i-1) in bufH0[(i-1)&3] ----
        const i32x4 hv = *(const i32x4*)&bufH0[(uu + 3) & 3][rd];
        const bf16x8 hf = __builtin_bit_cast(bf16x8, hv);
        f32x4 A0, A1;
        A0 = __builtin_amdgcn_mfma_f32_16x16x32_bf16(wfR[0], hf, cb[0], 0, 0, 0);
        A1 = __builtin_amdgcn_mfma_f32_16x16x32_bf16(wfR[1], hf, cb[1], 0, 0, 0);
        const float xt = (uu == 0) ? xv.x : (uu == 1) ? xv.y : (uu == 2) ? xv.z : xv.w;
        // regs ARE (i,f,g,o) of the owned units -- zero select
        CELL(fmaf(w0x[0][0], xt, A0[0]), fmaf(w0x[0][1], xt, A0[1]),
             fmaf(w0x[0][2], xt, A0[2]), fmaf(w0x[0][3], xt, A0[3]), cvA, hA);
        CELL(fmaf(w0x[1][0], xt, A1[0]), fmaf(w0x[1][1], xt, A1[1]),
             fmaf(w0x[1][2], xt, A1[2]), fmaf(w0x[1][3], xt, A1[3]), cvB, hB);
        int pk;
        asm("v_cvt_pk_bf16_f32 %0, %1, %2" : "=v"(pk) : "v"(hA), "v"(hB));
        bufH0[uu][wb] = pk;            // units (8V+2m, 8V+2m+1) = pair 4V+m
      } else {
        const bool doC = (uu >= 2) || (k > 0);   // compute h1(i-2)
        const bool doP = (uu >= 1) || (k > 0);   // prefetch h0(i-1)
        i32x4 h1v = {0, 0, 0, 0};
        if (doC) h1v = *(const i32x4*)&bufH1[(uu + 1) & 1][rd];  // h1(i-3)
        i32x4 h0next = h0pre;
        if (doP) h0next = *(const i32x4*)&bufH0[(uu + 3) & 3][rd]; // h0(i-1)
        if (doC) {
          const bf16x8 h0f = __builtin_bit_cast(bf16x8, h0pre);
          const bf16x8 h1f = __builtin_bit_cast(bf16x8, h1v);
          f32x4 A0, A1;
          __builtin_amdgcn_s_setprio(1);
          A0 = __builtin_amdgcn_mfma_f32_16x16x32_bf16(wfI[0], h0f, cb[0], 0, 0, 0);
          A1 = __builtin_amdgcn_mfma_f32_16x16x32_bf16(wfI[1], h0f, cb[1], 0, 0, 0);
          A0 = __builtin_amdgcn_mfma_f32_16x16x32_bf16(wfR[0], h1f, A0, 0, 0, 0);
          A1 = __builtin_amdgcn_mfma_f32_16x16x32_bf16(wfR[1], h1f, A1, 0, 0, 0);
          __builtin_amdgcn_s_setprio(0);
          CELL(A0[0], A0[1], A0[2], A0[3], cvA, hA);
          CELL(A1[0], A1[1], A1[2], A1[3], cvB, hB);
          int pk;
          asm("v_cvt_pk_bf16_f32 %0, %1, %2" : "=v"(pk) : "v"(hA), "v"(hB));
          bufH1[uu & 1][wb] = pk;      // h1(i-2) -> slot (i-2)&1 = i&1
        }
        h0pre = h0next;
      }
      __syncthreads();
    }
  }

  // ---- epilogue: L1 still owes h1(510), h1(511) ----
  if (isL1) {
    // h1(510) = f(h0(510)=h0pre, h1(509)=bufH1[1])
    const i32x4 h1v = *(const i32x4*)&bufH1[1][rd];
    const bf16x8 h0f = __builtin_bit_cast(bf16x8, h0pre);
    const bf16x8 h1f = __builtin_bit_cast(bf16x8, h1v);
    f32x4 A0, A1;
    A0 = __builtin_amdgcn_mfma_f32_16x16x32_bf16(wfI[0], h0f, cb[0], 0, 0, 0);
    A1 = __builtin_amdgcn_mfma_f32_16x16x32_bf16(wfI[1], h0f, cb[1], 0, 0, 0);
    A0 = __builtin_amdgcn_mfma_f32_16x16x32_bf16(wfR[0], h1f, A0, 0, 0, 0);
    A1 = __builtin_amdgcn_mfma_f32_16x16x32_bf16(wfR[1], h1f, A1, 0, 0, 0);
    CELL(A0[0], A0[1], A0[2], A0[3], cvA, hA);
    CELL(A1[0], A1[1], A1[2], A1[3], cvB, hB);
    int pk;
    asm("v_cvt_pk_bf16_f32 %0, %1, %2" : "=v"(pk) : "v"(hA), "v"(hB));
    bufH1[0][wb] = pk;                 // h1(510)
  }
  __syncthreads();
  if (isL1) {
    // h1(511) = f(h0(511)=bufH0[3], h1(510)=bufH1[0]); then FC partial
    const i32x4 h0v = *(const i32x4*)&bufH0[3][rd];
    const i32x4 h1v = *(const i32x4*)&bufH1[0][rd];
    const bf16x8 h0f = __builtin_bit_cast(bf16x8, h0v);
    const bf16x8 h1f = __builtin_bit_cast(bf16x8, h1v);
    f32x4 A0, A1;
    A0 = __builtin_amdgcn_mfma_f32_16x16x32_bf16(wfI[0], h0f, cb[0], 0, 0, 0);
    A1 = __builtin_amdgcn_mfma_f32_16x16x32_bf16(wfI[1], h0f, cb[1], 0, 0, 0);
    A0 = __builtin_amdgcn_mfma_f32_16x16x32_bf16(wfR[0], h1f, A0, 0, 0, 0);
    A1 = __builtin_amdgcn_mfma_f32_16x16x32_bf16(wfR[1], h1f, A1, 0, 0, 0);
    CELL(A0[0], A0[1], A0[2], A0[3], cvA, hA);
    CELL(A1[0], A1[1], A1[2], A1[3], cvB, hB);
    float part = hA * wfcA + hB * wfcB;
    part += __shfl_xor(part, 16);   // sum over m
    part += __shfl_xor(part, 32);
    if (l < 16) bufFC[V][l] = part;  // l<16 -> m==0, col=l
  }
  __syncthreads();
  if (w == 4 && l < 16) {
    const float o = bufFC[0][l] + bufFC[1][l] + bufFC[2][l] + bufFC[3][l] + bfc[0];
    out[blockIdx.x * 16 + l] = o > 0.f ? o : 0.f;
  }
}

extern "C" void kernel_launch(void* const* d_in, const int* in_sizes, int n_in,
                              void* d_out, int out_size, void* d_ws, size_t ws_size,
                              hipStream_t stream) {
  const float* x    = (const float*)d_in[0];
  const float* Wih0 = (const float*)d_in[1];
  const float* Whh0 = (const float*)d_in[2];
  const float* bih0 = (const float*)d_in[3];
  const float* bhh0 = (const float*)d_in[4];
  const float* Wih1 = (const float*)d_in[5];
  const float* Whh1 = (const float*)d_in[6];
  const float* bih1 = (const float*)d_in[7];
  const float* bhh1 = (const float*)d_in[8];
  const float* Wfc  = (const float*)d_in[9];
  const float* bfc  = (const float*)d_in[10];

  const int B = 4096;
  const int grid = B / 16;   // 256 blocks x 8 waves = 2048 waves -> 2/SIMD
  lstm2_zs2_kernel<<<grid, 512, 0, stream>>>(
      x, Wih0, Whh0, bih0, bhh0, Wih1, Whh1, bih1, bhh1, Wfc, bfc,
      (float*)d_out);
}

// Round 16
// 176.466 us; speedup vs baseline: 1.1863x; 1.0054x over previous
//
#include <hip/hip_runtime.h>
#include <hip/hip_bf16.h>

// 2-layer LSTM (H=32, T=512, I=1) + FC(1) + ReLU, fused, ZERO-SELECT
// 8-wave unit-split, 16 batches/block (R15 structure) + path micro-cuts:
//  * x prefetched one k (4 steps) ahead -> global-load latency off-path.
//  * L0 bias+x folded into MFMA C-in (cbx computed while LDS read is in
//    flight) -> no post-MFMA fma on the gate path.
//  * L1 parallel accumulators: P = wfI*h0 + cb, Q = wfR*h1 + 0 issue
//    back-to-back (independent), A = P + Q via v_add -> one MFMA latency
//    on the path instead of a serial C-in chain of two.
// Structure unchanged: adjacent-unit tiles (lane m owns units 8V+2m,+1),
// h-publish = 1 cvt_pk + 1 ds_write_b32; L1 lags 2 steps with h0 register
// prefetch (4-parity h0 buffer); zero gate select; merged-rcp CELL;
// one __syncthreads per step; pre-zeroed LDS. 256 blocks x 8 waves.

typedef __attribute__((ext_vector_type(8))) short bf16x8;
typedef __attribute__((ext_vector_type(4))) float f32x4;
typedef __attribute__((ext_vector_type(4))) int   i32x4;

#define HID 32
#define SEQ 512
#define L2E 1.4426950408889634f
#define LSTR 20   // LDS h-row stride in dwords (16 used + 4 pad, 16B-aligned)

static __device__ __forceinline__ float fexp2(float x){ return __builtin_amdgcn_exp2f(x); }
static __device__ __forceinline__ float frcp (float x){ return __builtin_amdgcn_rcpf(x); }
static __device__ __forceinline__ short f2bf(float f){
  unsigned u = __builtin_bit_cast(unsigned, f);
  u = (u + 0x7fffu + ((u >> 16) & 1u)) >> 16;
  return (short)u;
}

// fused LSTM cell, merged-rcp form. Gates pre-scaled (i,f,o by -log2e;
// g by +2log2e):  I=e^-i, F=e^-f, O=e^-o, G=e^{2g}.
#define CELL(gi, gf, gg, go, cvr, hout) do {                         \
  const float I_ = fexp2(gi), G_ = fexp2(gg);                        \
  const float F_ = fexp2(gf), O_ = fexp2(go);                        \
  const float a_ = 1.f + I_, b_ = 1.f + G_, c_ = 1.f + F_;           \
  const float P1_ = a_ * b_;                                         \
  const float R_  = frcp(c_ * P1_);                                  \
  const float fv_ = P1_ * R_;                                        \
  const float ig_ = (G_ - 1.f) * (c_ * R_);                          \
  (cvr) = fmaf(fv_, (cvr), ig_);                                     \
  const float C2_ = fexp2((cvr) * (2.f * L2E));                      \
  (hout) = (C2_ - 1.f) * frcp((1.f + O_) * (1.f + C2_));             \
} while (0)

__global__ __launch_bounds__(512, 2) void lstm2_zs3_kernel(
    const float* __restrict__ x,
    const float* __restrict__ Wih0, const float* __restrict__ Whh0,
    const float* __restrict__ bih0, const float* __restrict__ bhh0,
    const float* __restrict__ Wih1, const float* __restrict__ Whh1,
    const float* __restrict__ bih1, const float* __restrict__ bhh1,
    const float* __restrict__ Wfc, const float* __restrict__ bfc,
    float* __restrict__ out)
{
  const int tid = threadIdx.x;
  const int w   = tid >> 6;          // 0-3: L0 groups; 4-7: L1 groups
  const int l   = tid & 63;
  const int m   = l >> 4;            // k-group; owns units 8V+2m, 8V+2m+1
  const int col = l & 15;            // batch slot (16 batches/block)
  const int V   = w & 3;             // unit group: units 8V..8V+7
  const bool isL1 = (w >= 4);

  __shared__ int   bufH0[4][16 * LSTR];   // 4 parities (lag-2 prefetch)
  __shared__ int   bufH1[2][16 * LSTR];
  __shared__ float bufFC[4][16];

  // zero-init exchange buffers (kills all t=0 special cases)
  for (int i = tid; i < 4 * 16 * LSTR; i += 512) ((int*)bufH0)[i] = 0;
  for (int i = tid; i < 2 * 16 * LSTR; i += 512) ((int*)bufH1)[i] = 0;
  __syncthreads();

  // ---- weights: tile t row rho = gate(rho&3) of unit 8V+2*(rho>>2)+t.
  //      Lane supplies A row = col. Pre-scaled: i,f,o -> -log2e; g -> +2log2e.
  const float* Wrec = isL1 ? Whh1 : Whh0;
  const float* Bi   = isL1 ? bih1 : bih0;
  const float* Bh   = isL1 ? bhh1 : bhh0;
  const int   gcol  = col & 3;             // gate type this lane's A-row feeds
  const float scA   = (gcol == 2) ? (2.0f * L2E) : (-L2E);
  bf16x8 wfR[2], wfI[2];
  f32x4  cb[2];
  float  w0x[2][4];
  #pragma unroll
  for (int t = 0; t < 2; ++t) {
    const int ga = gcol * 32 + 8 * V + 2 * (col >> 2) + t;  // A-row unit's gate row
    #pragma unroll
    for (int j = 0; j < 8; ++j) {
      wfR[t][j] = f2bf(scA * Wrec[ga * HID + (8 * m + j)]);
      wfI[t][j] = isL1 ? f2bf(scA * Wih1[ga * HID + (8 * m + j)]) : (short)0;
    }
    const int uc = 8 * V + 2 * m + t;            // owned cell unit (tile t)
    #pragma unroll
    for (int rr = 0; rr < 4; ++rr) {
      const float sc = (rr == 2) ? (2.0f * L2E) : (-L2E);
      cb[t][rr]  = sc * (Bi[rr * 32 + uc] + Bh[rr * 32 + uc]);
      w0x[t][rr] = isL1 ? 0.f : sc * Wih0[rr * 32 + uc];
    }
  }
  const float wfcA = isL1 ? Wfc[8 * V + 2 * m]     : 0.f;
  const float wfcB = isL1 ? Wfc[8 * V + 2 * m + 1] : 0.f;

  float cvA = 0.f, cvB = 0.f, hA = 0.f, hB = 0.f;
  i32x4 h0pre = {0, 0, 0, 0};        // L1: h0(i-2) register prefetch
  const float* xb = x + (size_t)(blockIdx.x * 16 + col) * SEQ;
  const int  rd = col * LSTR + 4 * m;            // b128 read: units 8m..8m+7
  const int  wb = col * LSTR + 4 * V + m;        // b32 write: own unit pair

  float4 xcur = {0.f, 0.f, 0.f, 0.f};
  if (!isL1) xcur = *reinterpret_cast<const float4*>(xb);   // k = 0

  for (int k = 0; k < SEQ / 4; ++k) {
    float4 xnext = {0.f, 0.f, 0.f, 0.f};
    if (!isL1 && k + 1 < SEQ / 4)
      xnext = *reinterpret_cast<const float4*>(xb + (k + 1) * 4);  // prefetch
    #pragma unroll
    for (int uu = 0; uu < 4; ++uu) {
      if (!isL1) {
        // ---- L0: h0(i) from h0(i-1) in bufH0[(i-1)&3] ----
        const i32x4 hv = *(const i32x4*)&bufH0[(uu + 3) & 3][rd];
        const bf16x8 hf = __builtin_bit_cast(bf16x8, hv);
        const float xt = (uu == 0) ? xcur.x : (uu == 1) ? xcur.y
                       : (uu == 2) ? xcur.z : xcur.w;
        // bias + x folded into C-in (computes while LDS read is in flight)
        f32x4 cbx0, cbx1;
        #pragma unroll
        for (int rr = 0; rr < 4; ++rr) {
          cbx0[rr] = fmaf(w0x[0][rr], xt, cb[0][rr]);
          cbx1[rr] = fmaf(w0x[1][rr], xt, cb[1][rr]);
        }
        f32x4 A0, A1;
        A0 = __builtin_amdgcn_mfma_f32_16x16x32_bf16(wfR[0], hf, cbx0, 0, 0, 0);
        A1 = __builtin_amdgcn_mfma_f32_16x16x32_bf16(wfR[1], hf, cbx1, 0, 0, 0);
        // regs ARE (i,f,g,o) of the owned units -- zero select
        CELL(A0[0], A0[1], A0[2], A0[3], cvA, hA);
        CELL(A1[0], A1[1], A1[2], A1[3], cvB, hB);
        int pk;
        asm("v_cvt_pk_bf16_f32 %0, %1, %2" : "=v"(pk) : "v"(hA), "v"(hB));
        bufH0[uu][wb] = pk;            // units (8V+2m, 8V+2m+1) = pair 4V+m
      } else {
        const bool doC = (uu >= 2) || (k > 0);   // compute h1(i-2)
        const bool doP = (uu >= 1) || (k > 0);   // prefetch h0(i-1)
        i32x4 h1v = {0, 0, 0, 0};
        if (doC) h1v = *(const i32x4*)&bufH1[(uu + 1) & 1][rd];  // h1(i-3)
        i32x4 h0next = h0pre;
        if (doP) h0next = *(const i32x4*)&bufH0[(uu + 3) & 3][rd]; // h0(i-1)
        if (doC) {
          const bf16x8 h0f = __builtin_bit_cast(bf16x8, h0pre);
          const bf16x8 h1f = __builtin_bit_cast(bf16x8, h1v);
          const f32x4 z4 = {0.f, 0.f, 0.f, 0.f};
          f32x4 P0, P1, Q0, Q1;
          __builtin_amdgcn_s_setprio(1);
          P0 = __builtin_amdgcn_mfma_f32_16x16x32_bf16(wfI[0], h0f, cb[0], 0, 0, 0);
          P1 = __builtin_amdgcn_mfma_f32_16x16x32_bf16(wfI[1], h0f, cb[1], 0, 0, 0);
          Q0 = __builtin_amdgcn_mfma_f32_16x16x32_bf16(wfR[0], h1f, z4, 0, 0, 0);
          Q1 = __builtin_amdgcn_mfma_f32_16x16x32_bf16(wfR[1], h1f, z4, 0, 0, 0);
          __builtin_amdgcn_s_setprio(0);
          const f32x4 A0 = P0 + Q0;     // independent MFMAs complete in
          const f32x4 A1 = P1 + Q1;     // parallel; merge with v_add
          CELL(A0[0], A0[1], A0[2], A0[3], cvA, hA);
          CELL(A1[0], A1[1], A1[2], A1[3], cvB, hB);
          int pk;
          asm("v_cvt_pk_bf16_f32 %0, %1, %2" : "=v"(pk) : "v"(hA), "v"(hB));
          bufH1[uu & 1][wb] = pk;      // h1(i-2) -> slot (i-2)&1 = i&1
        }
        h0pre = h0next;
      }
      __syncthreads();
    }
    xcur = xnext;
  }

  // ---- epilogue: L1 still owes h1(510), h1(511) ----
  if (isL1) {
    // h1(510) = f(h0(510)=h0pre, h1(509)=bufH1[1])
    const i32x4 h1v = *(const i32x4*)&bufH1[1][rd];
    const bf16x8 h0f = __builtin_bit_cast(bf16x8, h0pre);
    const bf16x8 h1f = __builtin_bit_cast(bf16x8, h1v);
    f32x4 A0, A1;
    A0 = __builtin_amdgcn_mfma_f32_16x16x32_bf16(wfI[0], h0f, cb[0], 0, 0, 0);
    A1 = __builtin_amdgcn_mfma_f32_16x16x32_bf16(wfI[1], h0f, cb[1], 0, 0, 0);
    A0 = __builtin_amdgcn_mfma_f32_16x16x32_bf16(wfR[0], h1f, A0, 0, 0, 0);
    A1 = __builtin_amdgcn_mfma_f32_16x16x32_bf16(wfR[1], h1f, A1, 0, 0, 0);
    CELL(A0[0], A0[1], A0[2], A0[3], cvA, hA);
    CELL(A1[0], A1[1], A1[2], A1[3], cvB, hB);
    int pk;
    asm("v_cvt_pk_bf16_f32 %0, %1, %2" : "=v"(pk) : "v"(hA), "v"(hB));
    bufH1[0][wb] = pk;                 // h1(510)
  }
  __syncthreads();
  if (isL1) {
    // h1(511) = f(h0(511)=bufH0[3], h1(510)=bufH1[0]); then FC partial
    const i32x4 h0v = *(const i32x4*)&bufH0[3][rd];
    const i32x4 h1v = *(const i32x4*)&bufH1[0][rd];
    const bf16x8 h0f = __builtin_bit_cast(bf16x8, h0v);
    const bf16x8 h1f = __builtin_bit_cast(bf16x8, h1v);
    f32x4 A0, A1;
    A0 = __builtin_amdgcn_mfma_f32_16x16x32_bf16(wfI[0], h0f, cb[0], 0, 0, 0);
    A1 = __builtin_amdgcn_mfma_f32_16x16x32_bf16(wfI[1], h0f, cb[1], 0, 0, 0);
    A0 = __builtin_amdgcn_mfma_f32_16x16x32_bf16(wfR[0], h1f, A0, 0, 0, 0);
    A1 = __builtin_amdgcn_mfma_f32_16x16x32_bf16(wfR[1], h1f, A1, 0, 0, 0);
    CELL(A0[0], A0[1], A0[2], A0[3], cvA, hA);
    CELL(A1[0], A1[1], A1[2], A1[3], cvB, hB);
    float part = hA * wfcA + hB * wfcB;
    part += __shfl_xor(part, 16);   // sum over m
    part += __shfl_xor(part, 32);
    if (l < 16) bufFC[V][l] = part;  // l<16 -> m==0, col=l
  }
  __syncthreads();
  if (w == 4 && l < 16) {
    const float o = bufFC[0][l] + bufFC[1][l] + bufFC[2][l] + bufFC[3][l] + bfc[0];
    out[blockIdx.x * 16 + l] = o > 0.f ? o : 0.f;
  }
}

extern "C" void kernel_launch(void* const* d_in, const int* in_sizes, int n_in,
                              void* d_out, int out_size, void* d_ws, size_t ws_size,
                              hipStream_t stream) {
  const float* x    = (const float*)d_in[0];
  const float* Wih0 = (const float*)d_in[1];
  const float* Whh0 = (const float*)d_in[2];
  const float* bih0 = (const float*)d_in[3];
  const float* bhh0 = (const float*)d_in[4];
  const float* Wih1 = (const float*)d_in[5];
  const float* Whh1 = (const float*)d_in[6];
  const float* bih1 = (const float*)d_in[7];
  const float* bhh1 = (const float*)d_in[8];
  const float* Wfc  = (const float*)d_in[9];
  const float* bfc  = (const float*)d_in[10];

  const int B = 4096;
  const int grid = B / 16;   // 256 blocks x 8 waves = 2048 waves -> 2/SIMD
  lstm2_zs3_kernel<<<grid, 512, 0, stream>>>(
      x, Wih0, Whh0, bih0, bhh0, Wih1, Whh1, bih1, bhh1, Wfc, bfc,
      (float*)d_out);
}